// Round 12
// baseline (607.057 us; speedup 1.0000x reference)
//
#include <hip/hip_runtime.h>
#include <math.h>

#define T_STEPS 120
#define BATCH   1024

typedef __attribute__((ext_vector_type(8))) short bf16x8;
typedef __attribute__((ext_vector_type(4))) float f32x4;
typedef unsigned short u16;

// split f into hi (truncated bf16) + lo (RNE bf16 of remainder); f ~= hi+lo
// returns (hi << 16) | lo
__device__ __forceinline__ unsigned split2(float f) {
    union { float f; unsigned u; } a; a.f = f;
    unsigned hi = a.u >> 16;
    union { float f; unsigned u; } h; h.u = a.u & 0xFFFF0000u;
    union { float f; unsigned u; } b; b.f = f - h.f;
    unsigned rr = b.u + 0x7FFFu + ((b.u >> 16) & 1);
    return (hi << 16) | (rr >> 16);
}

// round-to-nearest-even bf16 (static weights / raw input; ~2^-9 relative)
__device__ __forceinline__ short bf16rne(float f) {
    union { float f; unsigned u; } a; a.f = f;
    unsigned r = a.u + 0x7FFFu + ((a.u >> 16) & 1);
    return (short)(r >> 16);
}

__device__ __forceinline__ float fast_sigmoid(float x) {
    float e = __expf(-x);
    return __builtin_amdgcn_rcpf(1.f + e);
}

// LDS-visibility-only barrier: does NOT drain vmcnt, so global prefetch
// loads and h stores stay in flight across the step boundary.
__device__ __forceinline__ void block_sync_lds() {
    asm volatile("s_waitcnt lgkmcnt(0)" ::: "memory");
    __builtin_amdgcn_sched_barrier(0);
    __builtin_amdgcn_s_barrier();
    __builtin_amdgcn_sched_barrier(0);
}

// ---------------------------------------------------------------------------
// x (B,T,132) fp32 -> bf16 hi plane (B,T,144), zero-padded (lo not needed:
// L1's x-term runs single-bf16).
// ---------------------------------------------------------------------------
__global__ __launch_bounds__(256)
void xconv(const float* __restrict__ x, u16* __restrict__ xhi)
{
    int idx = blockIdx.x * 256 + threadIdx.x;
    int k   = idx % 144;
    int bt  = idx / 144;
    float f = (k < 132) ? x[(size_t)bt * 132 + k] : 0.f;
    xhi[idx] = (u16)(unsigned short)bf16rne(f);
}

// ---------------------------------------------------------------------------
// Fused LSTM layer, producer/consumer SPLIT. TPB threads, grid = 64
// (16 batch rows per block).
//   h-waves (wid < U/16): recurrence z = xp + b + h@U, gates, scan.
//   x-waves (wid >= U/16): x@W one step ahead -> f32 partial planes in LDS.
// Weights single RNE-bf16, register-resident; activations hi/lo split
// (2-term MFMA) except x-term when !XLO (single-term). All waves fit the
// 128-VGPR cap at 4 waves/SIMD -> no spill. One lgkm-only barrier per step.
// ---------------------------------------------------------------------------
template<int U, int KXD, int KTX, int KTAIL, int TPB, bool XLO, bool LAST_ONLY>
__global__ __launch_bounds__(TPB, 1)
void lstm_fused(const u16* __restrict__ xhi, const u16* __restrict__ xlo,
                const float* __restrict__ W, int KIN,
                const float* __restrict__ Uw, const float* __restrict__ bias,
                u16* __restrict__ hhi, u16* __restrict__ hlo,
                float* __restrict__ hlast)
{
    constexpr int NZ  = 4 * U;
    constexpr int KTH = U / 32;
    constexpr int NB  = 16;
    constexpr int HPLANE = NB * U;              // u16 per h plane per buffer
    constexpr int NGRP = U / 16;                // h-wave count == x-wave count
    constexpr int XPSTRIDE = 20;                // f32; pad -> 2-way banks, 16B aligned
    static_assert(TPB == NGRP * 128, "h-waves + x-waves");

    __shared__ u16 hsh[4 * HPLANE];             // [buf][hi/lo][NB*U]
    __shared__ float xp[2 * NZ * XPSTRIDE];

    const int tid  = threadIdx.x;
    const int lane = tid & 63;
    const int wid  = tid >> 6;
    const int ln   = lane & 15;
    const int lq   = lane >> 4;
    const bool ish = (wid < NGRP);
    const int g    = ish ? wid : wid - NGRP;
    const int unit = g * 16 + ln;
    const int b0   = blockIdx.x * NB;

    if (ish) {
        // =================== h-wave ===================
        bf16x8 bwu[4][KTH];
#pragma unroll
        for (int p = 0; p < 4; ++p)
#pragma unroll
            for (int kt = 0; kt < KTH; ++kt)
#pragma unroll
                for (int e = 0; e < 8; ++e) {
                    int k = kt * 32 + lq * 8 + e;
                    bwu[p][kt][e] = bf16rne(Uw[(size_t)k * NZ + p * U + unit]);
                }
        float breg[4];
#pragma unroll
        for (int p = 0; p < 4; ++p) breg[p] = bias[p * U + unit];

        // h state init: zero both planes of buf0; c = 0
        u16* hw0 = hsh + ((unit >> 3) * NB + lq * 4) * 8 + (unit & 7);
        u16* hw1 = hw0 + 2 * HPLANE;
        float creg[4];
#pragma unroll
        for (int r = 0; r < 4; ++r) {
            creg[r] = 0.f;
            hw0[r * 8] = 0;
            hw0[HPLANE + r * 8] = 0;
        }

        const u16* hrd[2][KTH];
#pragma unroll
        for (int b = 0; b < 2; ++b)
#pragma unroll
            for (int kt = 0; kt < KTH; ++kt)
                hrd[b][kt] = hsh + b * 2 * HPLANE + ((kt * 4 + lq) * NB + ln) * 8;

        const float* xprd[2];
        xprd[0] = xp;
        xprd[1] = xp + (size_t)NZ * XPSTRIDE;

        size_t ho = ((size_t)(b0 + lq * 4) * T_STEPS) * U + unit;

        block_sync_lds();

#define HSTEP(CUR, OTH, tc)                                                     \
    {                                                                           \
        f32x4 acc[4];                                                           \
        _Pragma("unroll")                                                       \
        for (int p = 0; p < 4; ++p) {                                           \
            f32x4 v = *reinterpret_cast<const f32x4*>(                          \
                xprd[CUR] + (p * U + unit) * XPSTRIDE + lq * 4);                \
            acc[p][0] = v[0] + breg[p]; acc[p][1] = v[1] + breg[p];             \
            acc[p][2] = v[2] + breg[p]; acc[p][3] = v[3] + breg[p];             \
        }                                                                       \
        _Pragma("unroll")                                                       \
        for (int kt = 0; kt < KTH; ++kt) {                                      \
            bf16x8 ahh = *reinterpret_cast<const bf16x8*>(hrd[CUR][kt]);        \
            bf16x8 ahl = *reinterpret_cast<const bf16x8*>(hrd[CUR][kt] + HPLANE); \
            _Pragma("unroll")                                                   \
            for (int p = 0; p < 4; ++p) {                                       \
                acc[p] = __builtin_amdgcn_mfma_f32_16x16x32_bf16(ahh, bwu[p][kt], acc[p], 0, 0, 0); \
                acc[p] = __builtin_amdgcn_mfma_f32_16x16x32_bf16(ahl, bwu[p][kt], acc[p], 0, 0, 0); \
            }                                                                   \
        }                                                                       \
        _Pragma("unroll")                                                       \
        for (int r = 0; r < 4; ++r) {                                           \
            float si = fast_sigmoid(acc[0][r]);                                 \
            float sf = fast_sigmoid(acc[1][r]);                                 \
            float gg = fmaxf(acc[2][r], 0.f);                                   \
            float so = fast_sigmoid(acc[3][r]);                                 \
            float c  = sf * creg[r] + si * gg;                                  \
            creg[r] = c;                                                        \
            float h = so * fmaxf(c, 0.f);                                       \
            unsigned s = split2(h);                                             \
            u16* hw = (OTH) ? hw1 : hw0;                                        \
            hw[r * 8] = (u16)(s >> 16);                                         \
            hw[HPLANE + r * 8] = (u16)s;                                        \
            if constexpr (!LAST_ONLY) {                                         \
                size_t o = ho + (size_t)r * (T_STEPS * U) + (size_t)(tc) * U;   \
                hhi[o] = (u16)(s >> 16);                                        \
                hlo[o] = (u16)s;                                                \
            } else {                                                            \
                if ((tc) == T_STEPS - 1)                                        \
                    hlast[(size_t)(b0 + lq * 4 + r) * U + unit] = h;            \
            }                                                                   \
        }                                                                       \
        block_sync_lds();                                                       \
    }

        for (int t = 0; t < T_STEPS; t += 2) {
            HSTEP(0, 1, t)
            HSTEP(1, 0, t + 1)
        }
#undef HSTEP
    } else {
        // =================== x-wave ===================
        bf16x8 wxw[KTX][4];
#pragma unroll
        for (int kt = 0; kt < KTX; ++kt)
#pragma unroll
            for (int p = 0; p < 4; ++p)
#pragma unroll
                for (int e = 0; e < 8; ++e) {
                    int k = kt * 32 + lq * 8 + e;
                    wxw[kt][p][e] = (k < KIN) ? bf16rne(W[(size_t)k * NZ + p * U + unit])
                                              : (short)0;
                }

        const u16* pxh = xhi + ((size_t)(b0 + ln) * T_STEPS) * KXD + lq * 8;
        const u16* pxl = XLO ? (xlo + ((size_t)(b0 + ln) * T_STEPS) * KXD + lq * 8) : nullptr;

        float* xpw[2];
        xpw[0] = xp;
        xpw[1] = xp + (size_t)NZ * XPSTRIDE;

        // frags for step 0
        bf16x8 xfh[KTX] = {}, xfl[KTX] = {};
#pragma unroll
        for (int kt = 0; kt < KTX; ++kt)
            if (kt < KTX - 1 || lq < KTAIL) {
                xfh[kt] = *reinterpret_cast<const bf16x8*>(pxh + kt * 32);
                if constexpr (XLO)
                    xfl[kt] = *reinterpret_cast<const bf16x8*>(pxl + kt * 32);
            }

        // partial for t=0 into buf0
        {
            f32x4 xacc[4] = {};
#pragma unroll
            for (int kt = 0; kt < KTX; ++kt)
#pragma unroll
                for (int p = 0; p < 4; ++p) {
                    xacc[p] = __builtin_amdgcn_mfma_f32_16x16x32_bf16(xfh[kt], wxw[kt][p], xacc[p], 0, 0, 0);
                    if constexpr (XLO)
                        xacc[p] = __builtin_amdgcn_mfma_f32_16x16x32_bf16(xfl[kt], wxw[kt][p], xacc[p], 0, 0, 0);
                }
#pragma unroll
            for (int p = 0; p < 4; ++p)
                *reinterpret_cast<f32x4*>(xpw[0] + (p * U + unit) * XPSTRIDE + lq * 4) = xacc[p];
            // frags for step 1
            pxh += KXD; if constexpr (XLO) pxl += KXD;
#pragma unroll
            for (int kt = 0; kt < KTX; ++kt)
                if (kt < KTX - 1 || lq < KTAIL) {
                    xfh[kt] = *reinterpret_cast<const bf16x8*>(pxh + kt * 32);
                    if constexpr (XLO)
                        xfl[kt] = *reinterpret_cast<const bf16x8*>(pxl + kt * 32);
                }
        }

        block_sync_lds();

#define XSTEP(OTH, tc)                                                          \
    {                                                                           \
        if ((tc) + 1 < T_STEPS) {                                               \
            f32x4 xacc[4] = {};                                                 \
            _Pragma("unroll")                                                   \
            for (int kt = 0; kt < KTX; ++kt)                                    \
            _Pragma("unroll")                                                   \
            for (int p = 0; p < 4; ++p) {                                       \
                xacc[p] = __builtin_amdgcn_mfma_f32_16x16x32_bf16(xfh[kt], wxw[kt][p], xacc[p], 0, 0, 0); \
                if constexpr (XLO)                                              \
                    xacc[p] = __builtin_amdgcn_mfma_f32_16x16x32_bf16(xfl[kt], wxw[kt][p], xacc[p], 0, 0, 0); \
            }                                                                   \
            _Pragma("unroll")                                                   \
            for (int p = 0; p < 4; ++p)                                         \
                *reinterpret_cast<f32x4*>(xpw[OTH] + (p * U + unit) * XPSTRIDE + lq * 4) = xacc[p]; \
            if ((tc) + 2 < T_STEPS) {                                           \
                pxh += KXD; if constexpr (XLO) pxl += KXD;                      \
                _Pragma("unroll")                                               \
                for (int kt = 0; kt < KTX; ++kt)                                \
                    if (kt < KTX - 1 || lq < KTAIL) {                           \
                        xfh[kt] = *reinterpret_cast<const bf16x8*>(pxh + kt * 32); \
                        if constexpr (XLO)                                      \
                            xfl[kt] = *reinterpret_cast<const bf16x8*>(pxl + kt * 32); \
                    }                                                           \
            }                                                                   \
        }                                                                       \
        block_sync_lds();                                                       \
    }

        for (int t = 0; t < T_STEPS; t += 2) {
            XSTEP(1, t)
            XSTEP(0, t + 1)
        }
#undef XSTEP
    }
}

// Dense head: one wave per batch row. 64 ->relu-> 64 ->relu-> 32 -> 101 -> softmax
__global__ __launch_bounds__(256)
void dense_head(const float* __restrict__ h3,    // (B,64)
                const float* __restrict__ Wd1, const float* __restrict__ bd1,
                const float* __restrict__ Wd2, const float* __restrict__ bd2,
                const float* __restrict__ Wd3, const float* __restrict__ bd3,
                float* __restrict__ out)         // (B,101)
{
    __shared__ float s1[4][64];
    __shared__ float s2[4][32];
    const int w    = threadIdx.x >> 6;
    const int lane = threadIdx.x & 63;
    const int row  = blockIdx.x * 4 + w;

    float hval = h3[(size_t)row * 64 + lane];
    float a = bd1[lane];
#pragma unroll
    for (int k = 0; k < 64; ++k) {
        float hk = __shfl(hval, k, 64);
        a = fmaf(hk, Wd1[k * 64 + lane], a);
    }
    s1[w][lane] = fmaxf(a, 0.f);
    __syncthreads();

    if (lane < 32) {
        float a2 = bd2[lane];
#pragma unroll
        for (int k = 0; k < 64; ++k) a2 = fmaf(s1[w][k], Wd2[k * 32 + lane], a2);
        s2[w][lane] = fmaxf(a2, 0.f);
    }
    __syncthreads();

    float a0 = bd3[lane];
#pragma unroll
    for (int k = 0; k < 32; ++k) a0 = fmaf(s2[w][k], Wd3[k * 101 + lane], a0);
    float a1 = -INFINITY;
    if (lane < 37) {
        a1 = bd3[64 + lane];
#pragma unroll
        for (int k = 0; k < 32; ++k) a1 = fmaf(s2[w][k], Wd3[k * 101 + 64 + lane], a1);
    }

    float m = fmaxf(a0, a1);
#pragma unroll
    for (int off = 32; off > 0; off >>= 1) m = fmaxf(m, __shfl_xor(m, off, 64));
    float e0 = expf(a0 - m);
    float e1 = (lane < 37) ? expf(a1 - m) : 0.f;
    float s = e0 + e1;
#pragma unroll
    for (int off = 32; off > 0; off >>= 1) s += __shfl_xor(s, off, 64);

    out[(size_t)row * 101 + lane] = e0 / s;
    if (lane < 37) out[(size_t)row * 101 + 64 + lane] = e1 / s;
}

extern "C" void kernel_launch(void* const* d_in, const int* in_sizes, int n_in,
                              void* d_out, int out_size, void* d_ws, size_t ws_size,
                              hipStream_t stream) {
    const float* x   = (const float*)d_in[0];
    const float* W1  = (const float*)d_in[1];
    const float* U1  = (const float*)d_in[2];
    const float* b1  = (const float*)d_in[3];
    const float* W2  = (const float*)d_in[4];
    const float* U2  = (const float*)d_in[5];
    const float* b2  = (const float*)d_in[6];
    const float* W3  = (const float*)d_in[7];
    const float* U3  = (const float*)d_in[8];
    const float* b3  = (const float*)d_in[9];
    const float* Wd1 = (const float*)d_in[10];
    const float* bd1 = (const float*)d_in[11];
    const float* Wd2 = (const float*)d_in[12];
    const float* bd2 = (const float*)d_in[13];
    const float* Wd3 = (const float*)d_in[14];
    const float* bd3 = (const float*)d_in[15];

    // workspace (u16 units). x plane aliased by h2 planes after L1.
    u16* ws16 = (u16*)d_ws;
    u16* xhi  = ws16;                         // 1024*120*144 = 17,694,720
    u16* h2hi = ws16;                         // alias (x dead after L1)
    u16* h2lo = h2hi + 15728640;              // 1024*120*128; ends 31,457,280
    u16* h1hi = ws16 + 35389440;              // 1024*120*64 = 7,864,320
    u16* h1lo = h1hi + 7864320;               // ends 51,118,080
    float* h3 = (float*)(ws16 + 51118080);    // 1024*64 fp32

    // 1) pad/round input x -> bf16 plane
    xconv<<<(BATCH * T_STEPS * 144) / 256, 256, 0, stream>>>(x, xhi);
    // 2) layer 1: U=64, Kx 144 (5 tiles, tail half), x single-term
    lstm_fused<64, 144, 5, 2, 512, false, false><<<64, 512, 0, stream>>>(
        xhi, nullptr, W1, 132, U1, b1, h1hi, h1lo, nullptr);
    // 3) layer 2: U=128, Kx 64 (2 tiles), 16 waves (8h+8x), x hi/lo
    lstm_fused<128, 64, 2, 4, 1024, true, false><<<64, 1024, 0, stream>>>(
        h1hi, h1lo, W2, 64, U2, b2, h2hi, h2lo, nullptr);
    // 4) layer 3: U=64, Kx 128 (4 tiles), x hi/lo, last h only (fp32)
    lstm_fused<64, 128, 4, 4, 512, true, true><<<64, 512, 0, stream>>>(
        h2hi, h2lo, W3, 128, U3, b3, nullptr, nullptr, h3);
    // 5) dense head + softmax
    dense_head<<<BATCH / 4, 256, 0, stream>>>(h3, Wd1, bd1, Wd2, bd2, Wd3, bd3,
                                              (float*)d_out);
}

// Round 13
// 507.614 us; speedup vs baseline: 1.1959x; 1.1959x over previous
//
#include <hip/hip_runtime.h>
#include <math.h>

#define T_STEPS 120
#define BATCH   1024

typedef __attribute__((ext_vector_type(8))) short bf16x8;
typedef __attribute__((ext_vector_type(4))) float f32x4;
typedef unsigned short u16;

// split f into hi (truncated bf16) + lo (RNE bf16 of remainder); f ~= hi+lo
__device__ __forceinline__ unsigned split2(float f) {
    union { float f; unsigned u; } a; a.f = f;
    unsigned hi = a.u >> 16;
    union { float f; unsigned u; } h; h.u = a.u & 0xFFFF0000u;
    union { float f; unsigned u; } b; b.f = f - h.f;
    unsigned rr = b.u + 0x7FFFu + ((b.u >> 16) & 1);
    return (hi << 16) | (rr >> 16);
}

// round-to-nearest-even bf16 (static weights / feedforward activations)
__device__ __forceinline__ short bf16rne(float f) {
    union { float f; unsigned u; } a; a.f = f;
    unsigned r = a.u + 0x7FFFu + ((a.u >> 16) & 1);
    return (short)(r >> 16);
}

__device__ __forceinline__ float fast_sigmoid(float x) {
    float e = __expf(-x);
    return __builtin_amdgcn_rcpf(1.f + e);
}

// LDS-visibility-only barrier: does NOT drain vmcnt, so global prefetch
// loads and h stores stay in flight across the step boundary.
__device__ __forceinline__ void block_sync_lds() {
    asm volatile("s_waitcnt lgkmcnt(0)" ::: "memory");
    __builtin_amdgcn_sched_barrier(0);
    __builtin_amdgcn_s_barrier();
    __builtin_amdgcn_sched_barrier(0);
}

// ---------------------------------------------------------------------------
// x (B,T,132) fp32 -> bf16 hi plane (B,T,144), zero-padded.
// ---------------------------------------------------------------------------
__global__ __launch_bounds__(256)
void xconv(const float* __restrict__ x, u16* __restrict__ xhi)
{
    int idx = blockIdx.x * 256 + threadIdx.x;
    int k   = idx % 144;
    int bt  = idx / 144;
    float f = (k < 132) ? x[(size_t)bt * 132 + k] : 0.f;
    xhi[idx] = (u16)(unsigned short)bf16rne(f);
}

// ---------------------------------------------------------------------------
// Fused LSTM layer (L1/L3), producer/consumer SPLIT, 512 threads, grid 64.
//   h-waves (wid < U/16): recurrence z = xp + b + h@U, gates, scan.
//   x-waves (wid >= U/16): x@W one step ahead -> f32 partial planes in LDS.
// Weights single RNE-bf16 in registers; h activations hi/lo split.
// xp read deferred to gate stage (overlaps MFMA chain).
// ---------------------------------------------------------------------------
template<int U, int KXD, int KTX, int KTAIL, bool XLO, bool WLO, bool LAST_ONLY>
__global__ __launch_bounds__(512, 1)
void lstm_fused(const u16* __restrict__ xhi, const u16* __restrict__ xlo,
                const float* __restrict__ W, int KIN,
                const float* __restrict__ Uw, const float* __restrict__ bias,
                u16* __restrict__ hhi, u16* __restrict__ hlo,
                float* __restrict__ hlast)
{
    constexpr int NZ  = 4 * U;
    constexpr int KTH = U / 32;
    constexpr int NB  = 16;
    constexpr int HPLANE = NB * U;
    constexpr int NGRP = U / 16;
    constexpr int XPSTRIDE = 20;
    static_assert(NGRP * 128 == 512, "4 h-waves + 4 x-waves");

    __shared__ u16 hsh[4 * HPLANE];
    __shared__ float xp[2 * NZ * XPSTRIDE];

    const int tid  = threadIdx.x;
    const int lane = tid & 63;
    const int wid  = tid >> 6;
    const int ln   = lane & 15;
    const int lq   = lane >> 4;
    const bool ish = (wid < NGRP);
    const int g    = ish ? wid : wid - NGRP;
    const int unit = g * 16 + ln;
    const int b0   = blockIdx.x * NB;

    if (ish) {
        // =================== h-wave ===================
        bf16x8 bwu[4][KTH];
#pragma unroll
        for (int p = 0; p < 4; ++p)
#pragma unroll
            for (int kt = 0; kt < KTH; ++kt)
#pragma unroll
                for (int e = 0; e < 8; ++e) {
                    int k = kt * 32 + lq * 8 + e;
                    bwu[p][kt][e] = bf16rne(Uw[(size_t)k * NZ + p * U + unit]);
                }
        float breg[4];
#pragma unroll
        for (int p = 0; p < 4; ++p) breg[p] = bias[p * U + unit];

        u16* hw0 = hsh + ((unit >> 3) * NB + lq * 4) * 8 + (unit & 7);
        u16* hw1 = hw0 + 2 * HPLANE;
        float creg[4];
#pragma unroll
        for (int r = 0; r < 4; ++r) {
            creg[r] = 0.f;
            hw0[r * 8] = 0;
            hw0[HPLANE + r * 8] = 0;
        }

        const u16* hrd[2][KTH];
#pragma unroll
        for (int b = 0; b < 2; ++b)
#pragma unroll
            for (int kt = 0; kt < KTH; ++kt)
                hrd[b][kt] = hsh + b * 2 * HPLANE + ((kt * 4 + lq) * NB + ln) * 8;

        const float* xprd[2];
        xprd[0] = xp;
        xprd[1] = xp + (size_t)NZ * XPSTRIDE;

        size_t ho = ((size_t)(b0 + lq * 4) * T_STEPS) * U + unit;

        block_sync_lds();

#define HSTEP(CUR, OTH, tc)                                                     \
    {                                                                           \
        f32x4 xpv[4];                                                           \
        _Pragma("unroll")                                                       \
        for (int p = 0; p < 4; ++p)                                             \
            xpv[p] = *reinterpret_cast<const f32x4*>(                           \
                xprd[CUR] + (p * U + unit) * XPSTRIDE + lq * 4);                \
        f32x4 acc[4] = {};                                                      \
        _Pragma("unroll")                                                       \
        for (int kt = 0; kt < KTH; ++kt) {                                      \
            bf16x8 ahh = *reinterpret_cast<const bf16x8*>(hrd[CUR][kt]);        \
            bf16x8 ahl = *reinterpret_cast<const bf16x8*>(hrd[CUR][kt] + HPLANE); \
            _Pragma("unroll")                                                   \
            for (int p = 0; p < 4; ++p) {                                       \
                acc[p] = __builtin_amdgcn_mfma_f32_16x16x32_bf16(ahh, bwu[p][kt], acc[p], 0, 0, 0); \
                acc[p] = __builtin_amdgcn_mfma_f32_16x16x32_bf16(ahl, bwu[p][kt], acc[p], 0, 0, 0); \
            }                                                                   \
        }                                                                       \
        _Pragma("unroll")                                                       \
        for (int r = 0; r < 4; ++r) {                                           \
            float zi = acc[0][r] + xpv[0][r] + breg[0];                         \
            float zf = acc[1][r] + xpv[1][r] + breg[1];                         \
            float zg = acc[2][r] + xpv[2][r] + breg[2];                         \
            float zo = acc[3][r] + xpv[3][r] + breg[3];                         \
            float si = fast_sigmoid(zi);                                        \
            float sf = fast_sigmoid(zf);                                        \
            float gg = fmaxf(zg, 0.f);                                          \
            float so = fast_sigmoid(zo);                                        \
            float c  = sf * creg[r] + si * gg;                                  \
            creg[r] = c;                                                        \
            float h = so * fmaxf(c, 0.f);                                       \
            unsigned s = split2(h);                                             \
            u16* hw = (OTH) ? hw1 : hw0;                                        \
            hw[r * 8] = (u16)(s >> 16);                                         \
            hw[HPLANE + r * 8] = (u16)s;                                        \
            if constexpr (!LAST_ONLY) {                                         \
                size_t o = ho + (size_t)r * (T_STEPS * U) + (size_t)(tc) * U;   \
                hhi[o] = (u16)(s >> 16);                                        \
                if constexpr (WLO) hlo[o] = (u16)s;                             \
            } else {                                                            \
                if ((tc) == T_STEPS - 1)                                        \
                    hlast[(size_t)(b0 + lq * 4 + r) * U + unit] = h;            \
            }                                                                   \
        }                                                                       \
        block_sync_lds();                                                       \
    }

        for (int t = 0; t < T_STEPS; t += 2) {
            HSTEP(0, 1, t)
            HSTEP(1, 0, t + 1)
        }
#undef HSTEP
    } else {
        // =================== x-wave ===================
        bf16x8 wxw[KTX][4];
#pragma unroll
        for (int kt = 0; kt < KTX; ++kt)
#pragma unroll
            for (int p = 0; p < 4; ++p)
#pragma unroll
                for (int e = 0; e < 8; ++e) {
                    int k = kt * 32 + lq * 8 + e;
                    wxw[kt][p][e] = (k < KIN) ? bf16rne(W[(size_t)k * NZ + p * U + unit])
                                              : (short)0;
                }

        const u16* pxh = xhi + ((size_t)(b0 + ln) * T_STEPS) * KXD + lq * 8;
        const u16* pxl = XLO ? (xlo + ((size_t)(b0 + ln) * T_STEPS) * KXD + lq * 8) : nullptr;

        float* xpw[2];
        xpw[0] = xp;
        xpw[1] = xp + (size_t)NZ * XPSTRIDE;

        bf16x8 xfh[KTX] = {}, xfl[KTX] = {};
#pragma unroll
        for (int kt = 0; kt < KTX; ++kt)
            if (kt < KTX - 1 || lq < KTAIL) {
                xfh[kt] = *reinterpret_cast<const bf16x8*>(pxh + kt * 32);
                if constexpr (XLO)
                    xfl[kt] = *reinterpret_cast<const bf16x8*>(pxl + kt * 32);
            }

        {
            f32x4 xacc[4] = {};
#pragma unroll
            for (int kt = 0; kt < KTX; ++kt)
#pragma unroll
                for (int p = 0; p < 4; ++p) {
                    xacc[p] = __builtin_amdgcn_mfma_f32_16x16x32_bf16(xfh[kt], wxw[kt][p], xacc[p], 0, 0, 0);
                    if constexpr (XLO)
                        xacc[p] = __builtin_amdgcn_mfma_f32_16x16x32_bf16(xfl[kt], wxw[kt][p], xacc[p], 0, 0, 0);
                }
#pragma unroll
            for (int p = 0; p < 4; ++p)
                *reinterpret_cast<f32x4*>(xpw[0] + (p * U + unit) * XPSTRIDE + lq * 4) = xacc[p];
            pxh += KXD; if constexpr (XLO) pxl += KXD;
#pragma unroll
            for (int kt = 0; kt < KTX; ++kt)
                if (kt < KTX - 1 || lq < KTAIL) {
                    xfh[kt] = *reinterpret_cast<const bf16x8*>(pxh + kt * 32);
                    if constexpr (XLO)
                        xfl[kt] = *reinterpret_cast<const bf16x8*>(pxl + kt * 32);
                }
        }

        block_sync_lds();

#define XSTEP(OTH, tc)                                                          \
    {                                                                           \
        if ((tc) + 1 < T_STEPS) {                                               \
            f32x4 xacc[4] = {};                                                 \
            _Pragma("unroll")                                                   \
            for (int kt = 0; kt < KTX; ++kt)                                    \
            _Pragma("unroll")                                                   \
            for (int p = 0; p < 4; ++p) {                                       \
                xacc[p] = __builtin_amdgcn_mfma_f32_16x16x32_bf16(xfh[kt], wxw[kt][p], xacc[p], 0, 0, 0); \
                if constexpr (XLO)                                              \
                    xacc[p] = __builtin_amdgcn_mfma_f32_16x16x32_bf16(xfl[kt], wxw[kt][p], xacc[p], 0, 0, 0); \
            }                                                                   \
            _Pragma("unroll")                                                   \
            for (int p = 0; p < 4; ++p)                                         \
                *reinterpret_cast<f32x4*>(xpw[OTH] + (p * U + unit) * XPSTRIDE + lq * 4) = xacc[p]; \
            if ((tc) + 2 < T_STEPS) {                                           \
                pxh += KXD; if constexpr (XLO) pxl += KXD;                      \
                _Pragma("unroll")                                               \
                for (int kt = 0; kt < KTX; ++kt)                                \
                    if (kt < KTX - 1 || lq < KTAIL) {                           \
                        xfh[kt] = *reinterpret_cast<const bf16x8*>(pxh + kt * 32); \
                        if constexpr (XLO)                                      \
                            xfl[kt] = *reinterpret_cast<const bf16x8*>(pxl + kt * 32); \
                    }                                                           \
            }                                                                   \
        }                                                                       \
        block_sync_lds();                                                       \
    }

        for (int t = 0; t < T_STEPS; t += 2) {
            XSTEP(1, t)
            XSTEP(0, t + 1)
        }
#undef XSTEP
    }
}

// ---------------------------------------------------------------------------
// L2 (U=128): 512 threads = 8 combined waves, each owns 16 units.
// z = b + h1_t @ W2 (x-part, W2 in LDS, h1-hi only) + h @ U2 (hi/lo, U2 regs).
// Per-wave regs ~115 < 128 budget -> no spill. Grid 64.
// ---------------------------------------------------------------------------
__global__ __launch_bounds__(512, 1)
void lstm_l2(const u16* __restrict__ xhi,    // h1hi (B,T,64)
             const float* __restrict__ W,    // (64,512)
             const float* __restrict__ Uw,   // (128,512)
             const float* __restrict__ bias, // (512)
             u16* __restrict__ hhi, u16* __restrict__ hlo)  // (B,T,128)
{
    constexpr int U = 128, NZ = 512, KTH = 4, NB = 16, KXD = 64, KTX = 2;
    constexpr int HPLANE = NB * U;              // 2048 u16
    __shared__ u16 hsh[4 * HPLANE];             // 16 KB
    __shared__ u16 Wl[KXD * NZ];                // 64 KB, tiled [k>>3][n][k&7]

    const int tid  = threadIdx.x;
    const int lane = tid & 63;
    const int wid  = tid >> 6;
    const int ln   = lane & 15;
    const int lq   = lane >> 4;
    const int unit = wid * 16 + ln;
    const int b0   = blockIdx.x * NB;

    // stage W2 into LDS (coalesced global reads), bf16
    for (int idx = tid; idx < KXD * NZ; idx += 512) {
        int k = idx >> 9, n = idx & (NZ - 1);
        Wl[((k >> 3) * NZ + n) * 8 + (k & 7)] = (u16)bf16rne(W[(size_t)k * NZ + n]);
    }

    // U2 into registers (64 VGPR)
    bf16x8 bwu[4][KTH];
#pragma unroll
    for (int p = 0; p < 4; ++p)
#pragma unroll
        for (int kt = 0; kt < KTH; ++kt)
#pragma unroll
            for (int e = 0; e < 8; ++e) {
                int k = kt * 32 + lq * 8 + e;
                bwu[p][kt][e] = bf16rne(Uw[(size_t)k * NZ + p * U + unit]);
            }
    float breg[4];
#pragma unroll
    for (int p = 0; p < 4; ++p) breg[p] = bias[p * U + unit];

    u16* hw0 = hsh + ((unit >> 3) * NB + lq * 4) * 8 + (unit & 7);
    u16* hw1 = hw0 + 2 * HPLANE;
    float creg[4];
#pragma unroll
    for (int r = 0; r < 4; ++r) {
        creg[r] = 0.f;
        hw0[r * 8] = 0;
        hw0[HPLANE + r * 8] = 0;
    }

    const u16* hrd[2][KTH];
#pragma unroll
    for (int b = 0; b < 2; ++b)
#pragma unroll
        for (int kt = 0; kt < KTH; ++kt)
            hrd[b][kt] = hsh + b * 2 * HPLANE + ((kt * 4 + lq) * NB + ln) * 8;

    // W-frag base: frag(kt,p) at wb + (kt*4*NZ + p*U)*8 elements (imm offsets)
    const u16* wb = Wl + ((size_t)lq * NZ + unit) * 8;

    const u16* pxh = xhi + ((size_t)(b0 + ln) * T_STEPS) * KXD + lq * 8;
    bf16x8 xfh[KTX];
#pragma unroll
    for (int kt = 0; kt < KTX; ++kt)
        xfh[kt] = *reinterpret_cast<const bf16x8*>(pxh + kt * 32);

    size_t ho = ((size_t)(b0 + lq * 4) * T_STEPS) * U + unit;

    block_sync_lds();

#define L2STEP(CUR, OTH, tc)                                                    \
    {                                                                           \
        f32x4 acc[4] = {};                                                      \
        _Pragma("unroll")                                                       \
        for (int kt = 0; kt < KTH; ++kt) {                                      \
            bf16x8 ahh = *reinterpret_cast<const bf16x8*>(hrd[CUR][kt]);        \
            bf16x8 ahl = *reinterpret_cast<const bf16x8*>(hrd[CUR][kt] + HPLANE); \
            _Pragma("unroll")                                                   \
            for (int p = 0; p < 4; ++p) {                                       \
                acc[p] = __builtin_amdgcn_mfma_f32_16x16x32_bf16(ahh, bwu[p][kt], acc[p], 0, 0, 0); \
                acc[p] = __builtin_amdgcn_mfma_f32_16x16x32_bf16(ahl, bwu[p][kt], acc[p], 0, 0, 0); \
            }                                                                   \
        }                                                                       \
        _Pragma("unroll")                                                       \
        for (int kt = 0; kt < KTX; ++kt)                                        \
        _Pragma("unroll")                                                       \
        for (int p = 0; p < 4; ++p) {                                           \
            bf16x8 wf = *reinterpret_cast<const bf16x8*>(wb + (kt * 4 * NZ + p * U) * 8); \
            acc[p] = __builtin_amdgcn_mfma_f32_16x16x32_bf16(xfh[kt], wf, acc[p], 0, 0, 0); \
        }                                                                       \
        if ((tc) + 1 < T_STEPS) {                                               \
            pxh += KXD;                                                         \
            _Pragma("unroll")                                                   \
            for (int kt = 0; kt < KTX; ++kt)                                    \
                xfh[kt] = *reinterpret_cast<const bf16x8*>(pxh + kt * 32);      \
        }                                                                       \
        _Pragma("unroll")                                                       \
        for (int r = 0; r < 4; ++r) {                                           \
            float si = fast_sigmoid(acc[0][r] + breg[0]);                       \
            float sf = fast_sigmoid(acc[1][r] + breg[1]);                       \
            float gg = fmaxf(acc[2][r] + breg[2], 0.f);                         \
            float so = fast_sigmoid(acc[3][r] + breg[3]);                       \
            float c  = sf * creg[r] + si * gg;                                  \
            creg[r] = c;                                                        \
            float h = so * fmaxf(c, 0.f);                                       \
            unsigned s = split2(h);                                             \
            u16* hw = (OTH) ? hw1 : hw0;                                        \
            hw[r * 8] = (u16)(s >> 16);                                         \
            hw[HPLANE + r * 8] = (u16)s;                                        \
            size_t o = ho + (size_t)r * (T_STEPS * U) + (size_t)(tc) * U;       \
            hhi[o] = (u16)(s >> 16);                                            \
            hlo[o] = (u16)s;                                                    \
        }                                                                       \
        block_sync_lds();                                                       \
    }

    for (int t = 0; t < T_STEPS; t += 2) {
        L2STEP(0, 1, t)
        L2STEP(1, 0, t + 1)
    }
#undef L2STEP
}

// Dense head: one wave per batch row. 64 ->relu-> 64 ->relu-> 32 -> 101 -> softmax
__global__ __launch_bounds__(256)
void dense_head(const float* __restrict__ h3,    // (B,64)
                const float* __restrict__ Wd1, const float* __restrict__ bd1,
                const float* __restrict__ Wd2, const float* __restrict__ bd2,
                const float* __restrict__ Wd3, const float* __restrict__ bd3,
                float* __restrict__ out)         // (B,101)
{
    __shared__ float s1[4][64];
    __shared__ float s2[4][32];
    const int w    = threadIdx.x >> 6;
    const int lane = threadIdx.x & 63;
    const int row  = blockIdx.x * 4 + w;

    float hval = h3[(size_t)row * 64 + lane];
    float a = bd1[lane];
#pragma unroll
    for (int k = 0; k < 64; ++k) {
        float hk = __shfl(hval, k, 64);
        a = fmaf(hk, Wd1[k * 64 + lane], a);
    }
    s1[w][lane] = fmaxf(a, 0.f);
    __syncthreads();

    if (lane < 32) {
        float a2 = bd2[lane];
#pragma unroll
        for (int k = 0; k < 64; ++k) a2 = fmaf(s1[w][k], Wd2[k * 32 + lane], a2);
        s2[w][lane] = fmaxf(a2, 0.f);
    }
    __syncthreads();

    float a0 = bd3[lane];
#pragma unroll
    for (int k = 0; k < 32; ++k) a0 = fmaf(s2[w][k], Wd3[k * 101 + lane], a0);
    float a1 = -INFINITY;
    if (lane < 37) {
        a1 = bd3[64 + lane];
#pragma unroll
        for (int k = 0; k < 32; ++k) a1 = fmaf(s2[w][k], Wd3[k * 101 + 64 + lane], a1);
    }

    float m = fmaxf(a0, a1);
#pragma unroll
    for (int off = 32; off > 0; off >>= 1) m = fmaxf(m, __shfl_xor(m, off, 64));
    float e0 = expf(a0 - m);
    float e1 = (lane < 37) ? expf(a1 - m) : 0.f;
    float s = e0 + e1;
#pragma unroll
    for (int off = 32; off > 0; off >>= 1) s += __shfl_xor(s, off, 64);

    out[(size_t)row * 101 + lane] = e0 / s;
    if (lane < 37) out[(size_t)row * 101 + 64 + lane] = e1 / s;
}

extern "C" void kernel_launch(void* const* d_in, const int* in_sizes, int n_in,
                              void* d_out, int out_size, void* d_ws, size_t ws_size,
                              hipStream_t stream) {
    const float* x   = (const float*)d_in[0];
    const float* W1  = (const float*)d_in[1];
    const float* U1  = (const float*)d_in[2];
    const float* b1  = (const float*)d_in[3];
    const float* W2  = (const float*)d_in[4];
    const float* U2  = (const float*)d_in[5];
    const float* b2  = (const float*)d_in[6];
    const float* W3  = (const float*)d_in[7];
    const float* U3  = (const float*)d_in[8];
    const float* b3  = (const float*)d_in[9];
    const float* Wd1 = (const float*)d_in[10];
    const float* bd1 = (const float*)d_in[11];
    const float* Wd2 = (const float*)d_in[12];
    const float* bd2 = (const float*)d_in[13];
    const float* Wd3 = (const float*)d_in[14];
    const float* bd3 = (const float*)d_in[15];

    // workspace (u16 units). x plane aliased by h2 planes after L1.
    u16* ws16 = (u16*)d_ws;
    u16* xhi  = ws16;                         // 1024*120*144 = 17,694,720
    u16* h2hi = ws16;                         // alias (x dead after L1)
    u16* h2lo = h2hi + 15728640;              // 1024*120*128; ends 31,457,280
    u16* h1hi = ws16 + 35389440;              // 1024*120*64 = 7,864,320
    float* h3 = (float*)(ws16 + 51118080);    // 1024*64 fp32

    // 1) pad/round input x -> bf16 plane
    xconv<<<(BATCH * T_STEPS * 144) / 256, 256, 0, stream>>>(x, xhi);
    // 2) layer 1: U=64, Kx 144 (5 tiles, tail half), x single-term, hi-only out
    lstm_fused<64, 144, 5, 2, false, false, false><<<64, 512, 0, stream>>>(
        xhi, nullptr, W1, 132, U1, b1, h1hi, nullptr, nullptr);
    // 3) layer 2: U=128, combined waves, W2 in LDS, x = h1-hi only
    lstm_l2<<<64, 512, 0, stream>>>(h1hi, W2, U2, b2, h2hi, h2lo);
    // 4) layer 3: U=64, Kx 128 (4 tiles), x hi/lo, last h only (fp32)
    lstm_fused<64, 128, 4, 4, true, true, true><<<64, 512, 0, stream>>>(
        h2hi, h2lo, W3, 128, U3, b3, nullptr, nullptr, h3);
    // 5) dense head + softmax
    dense_head<<<BATCH / 4, 256, 0, stream>>>(h3, Wd1, bd1, Wd2, bd2, Wd3, bd3,
                                              (float*)d_out);
}